// Round 3
// baseline (434.970 us; speedup 1.0000x reference)
//
#include <hip/hip_runtime.h>
#include <hip/hip_bf16.h>

#define INFEAT 4096
#define OUTFEAT 11008
#define TOKENS 2048

typedef int v4i __attribute__((ext_vector_type(4)));
typedef __bf16 bf16_t;
typedef bf16_t bf16x4 __attribute__((ext_vector_type(4)));
typedef bf16_t bf16x8 __attribute__((ext_vector_type(8)));
typedef float f32x4 __attribute__((ext_vector_type(4)));

__device__ __forceinline__ void async_copy16(const void* g, void* l) {
    __builtin_amdgcn_global_load_lds((const __attribute__((address_space(1))) void*)g,
                                     (__attribute__((address_space(3))) void*)l,
                                     16, 0, 0);
}

// ---- pre-pass: per-token i8 quantization of x; emits xq (packed words),
// ---- xscale[m] = amax/127, xsum[m] = sum of quantized ints (for zero-point fix)
__global__ __launch_bounds__(256) void quant_x(
    const float* __restrict__ x, unsigned int* __restrict__ xq,
    float* __restrict__ xscale, int* __restrict__ xsum)
{
    __shared__ float smax[4];
    __shared__ int ssum[4];
    const int row = blockIdx.x;
    const int tid = threadIdx.x;
    const int lane = tid & 63, wid = tid >> 6;
    const float* xr = x + (size_t)row * INFEAT;

    float4 v[4];
    #pragma unroll
    for (int i = 0; i < 4; ++i) v[i] = *(const float4*)&xr[tid * 16 + i * 4];

    float am = 0.f;
    #pragma unroll
    for (int i = 0; i < 4; ++i)
        am = fmaxf(am, fmaxf(fmaxf(fabsf(v[i].x), fabsf(v[i].y)),
                             fmaxf(fabsf(v[i].z), fabsf(v[i].w))));
    #pragma unroll
    for (int o = 32; o > 0; o >>= 1) am = fmaxf(am, __shfl_xor(am, o, 64));
    if (lane == 0) smax[wid] = am;
    __syncthreads();
    am = fmaxf(fmaxf(smax[0], smax[1]), fmaxf(smax[2], smax[3]));
    const float inv = am > 0.f ? 127.0f / am : 0.f;
    const float sc  = am > 0.f ? am / 127.0f : 0.f;

    int lsum = 0;
    unsigned int pk[4];
    #pragma unroll
    for (int i = 0; i < 4; ++i) {
        int q0 = (int)rintf(fminf(fmaxf(v[i].x * inv, -127.f), 127.f));
        int q1 = (int)rintf(fminf(fmaxf(v[i].y * inv, -127.f), 127.f));
        int q2 = (int)rintf(fminf(fmaxf(v[i].z * inv, -127.f), 127.f));
        int q3 = (int)rintf(fminf(fmaxf(v[i].w * inv, -127.f), 127.f));
        lsum += q0 + q1 + q2 + q3;
        pk[i] = (q0 & 255) | ((q1 & 255) << 8) | ((q2 & 255) << 16) | ((unsigned)(q3 & 255) << 24);
    }
    *(uint4*)&xq[(size_t)row * (INFEAT / 4) + tid * 4] = *(uint4*)pk;

    #pragma unroll
    for (int o = 32; o > 0; o >>= 1) lsum += __shfl_xor(lsum, o, 64);
    if (lane == 0) ssum[wid] = lsum;
    __syncthreads();
    if (tid == 0) {
        xsum[row] = ssum[0] + ssum[1] + ssum[2] + ssum[3];
        xscale[row] = sc;
    }
}

// ---- main GEMM: i8 MFMA, both operands via global_load_lds, XOR-swizzled LDS.
// A LDS: bytes [128 m][128 k], 16B chunk c stored at slot c^(m&7).
// B LDS: words [32 kp][128 n], word col c stored at c^(16*((kp>>2)&1)).
__global__ __launch_bounds__(256) void q3gemm_i8(
    const unsigned int* __restrict__ xq, const unsigned int* __restrict__ qw,
    const float* __restrict__ scales, const int* __restrict__ zeros,
    const float* __restrict__ bias, const float* __restrict__ xscale,
    const int* __restrict__ xsum, float* __restrict__ out)
{
    __shared__ unsigned int Als[128 * 32];   // 16 KB, byte view [128][128]
    __shared__ unsigned int Bls[32 * 128];   // 16 KB, word view [32][128]

    const int tid = threadIdx.x;
    // block swizzle: 16 consecutive blocks share one n-panel (L2 reuse of qw)
    const int n0 = (blockIdx.x >> 4) * 128;
    const int m0 = (blockIdx.x & 15) * 128;

    const int wid = tid >> 6, lane = tid & 63;
    const int wm = (wid & 1) * 64, wn = (wid >> 1) * 64;
    const int lr = lane & 15, lq = lane >> 4;

    // DMA decomposition
    const int a_row_s = wid * 32 + (lane >> 3);   // + p*8
    const int a_slot  = lane & 7;
    const int b_row_s = wid * 8 + (lane >> 5);    // + p*2
    const int b_grp   = lane & 31;

    v4i acc[4][4];
    #pragma unroll
    for (int i = 0; i < 4; ++i)
        #pragma unroll
        for (int j = 0; j < 4; ++j)
            acc[i][j] = (v4i){0, 0, 0, 0};

    for (int kt = 0; kt < INFEAT / 128; ++kt) {
        const int kp0 = kt * 32;   // packed-word row offset

        #pragma unroll
        for (int p = 0; p < 4; ++p) {
            const int m = a_row_s + p * 8;
            const int c = a_slot ^ (m & 7);
            async_copy16(&xq[(size_t)(m0 + m) * (INFEAT / 4) + kp0 + c * 4],
                         (char*)Als + (wid * 32 + p * 8) * 128);
        }
        #pragma unroll
        for (int p = 0; p < 4; ++p) {
            const int r = b_row_s + p * 2;
            const int g = b_grp ^ (((r >> 2) & 1) * 4);
            async_copy16(&qw[(size_t)(kp0 + r) * OUTFEAT + n0 + g * 4],
                         (char*)Bls + (wid * 8 + p * 2) * 512);
        }

        __syncthreads();

        #pragma unroll
        for (int ks = 0; ks < 2; ++ks) {
            v4i af[4];
            #pragma unroll
            for (int t = 0; t < 4; ++t) {
                const int m = wm + t * 16 + lr;
                const int slot = (ks * 4 + lq) ^ (m & 7);
                af[t] = *(const v4i*)((const char*)Als + m * 128 + slot * 16);
            }
            #pragma unroll
            for (int j = 0; j < 4; ++j) {
                const int csw = (wn + j * 16 + lr) ^ ((lq & 1) * 16);
                const int rb2 = ks * 16 + lq * 4;
                v4i bf;
                bf[0] = (int)(Bls[(rb2 + 0) * 128 + csw] ^ 0x80808080u);
                bf[1] = (int)(Bls[(rb2 + 1) * 128 + csw] ^ 0x80808080u);
                bf[2] = (int)(Bls[(rb2 + 2) * 128 + csw] ^ 0x80808080u);
                bf[3] = (int)(Bls[(rb2 + 3) * 128 + csw] ^ 0x80808080u);
                #pragma unroll
                for (int i = 0; i < 4; ++i)
                    acc[i][j] = __builtin_amdgcn_mfma_i32_16x16x64_i8(af[i], bf, acc[i][j], 0, 0, 0);
            }
        }

        __syncthreads();
    }

    // epilogue: out = sx[m]*s[n]*(acc + (128-z[n])*xsum[m]) + bias[n]
    #pragma unroll
    for (int j = 0; j < 4; ++j) {
        const int col = n0 + wn + j * 16 + lr;
        const float sn = scales[col];
        const int zi = 128 - zeros[col];
        const float bv = bias[col];
        #pragma unroll
        for (int i = 0; i < 4; ++i) {
            const int rb = m0 + wm + i * 16 + lq * 4;
            const float4 sx4 = *(const float4*)&xscale[rb];
            const int4 xs4 = *(const int4*)&xsum[rb];
            const float sxa[4] = {sx4.x, sx4.y, sx4.z, sx4.w};
            const int xsa[4] = {xs4.x, xs4.y, xs4.z, xs4.w};
            #pragma unroll
            for (int r = 0; r < 4; ++r) {
                const int tot = acc[i][j][r] + zi * xsa[r];
                out[(size_t)(rb + r) * OUTFEAT + col] = sxa[r] * sn * (float)tot + bv;
            }
        }
    }
}

// ---------------- fallback (round-1 fused kernel, used if ws too small) ----
#define LDSS 72
__global__ __launch_bounds__(256) void q3gemm_fb(
    const float* __restrict__ x, const unsigned int* __restrict__ qw,
    const float* __restrict__ scales, const int* __restrict__ zeros,
    const float* __restrict__ bias, float* __restrict__ out)
{
    __shared__ bf16_t Als[128 * LDSS];
    __shared__ bf16_t Bls[128 * LDSS];
    const int tid = threadIdx.x;
    const int m0 = blockIdx.y * 128;
    const int n0 = blockIdx.x * 128;
    const int bcol = tid & 127;
    const int bpr  = tid >> 7;
    const float scf = scales[n0 + bcol];
    const float nzs = (float)zeros[n0 + bcol] * scf;
    const int acolg = tid & 15;
    const int arow0 = tid >> 4;
    const int wid  = tid >> 6;
    const int lane = tid & 63;
    const int wm = (wid & 1) * 64;
    const int wn = (wid >> 1) * 64;
    const int lr = lane & 15;
    const int lq = lane >> 4;
    f32x4 acc[4][4];
    #pragma unroll
    for (int i = 0; i < 4; ++i)
        #pragma unroll
        for (int j = 0; j < 4; ++j) acc[i][j] = (f32x4)0.0f;
    for (int kt = 0; kt < INFEAT / 64; ++kt) {
        const int k0 = kt * 64;
        #pragma unroll
        for (int p = 0; p < 8; ++p) {
            const int row = arow0 + p * 16;
            const float4 v = *(const float4*)&x[(size_t)(m0 + row) * INFEAT + k0 + acolg * 4];
            bf16x4 b;
            b[0] = (bf16_t)v.x; b[1] = (bf16_t)v.y; b[2] = (bf16_t)v.z; b[3] = (bf16_t)v.w;
            *(bf16x4*)&Als[row * LDSS + acolg * 4] = b;
        }
        const int kp0 = k0 >> 2;
        #pragma unroll
        for (int it = 0; it < 8; ++it) {
            const int prel = it * 2 + bpr;
            const unsigned int q = qw[(size_t)(kp0 + prel) * OUTFEAT + n0 + bcol];
            bf16x4 b;
            b[0] = (bf16_t)((float)(q & 0xFFu)        * scf - nzs);
            b[1] = (bf16_t)((float)((q >> 8) & 0xFFu) * scf - nzs);
            b[2] = (bf16_t)((float)((q >> 16) & 0xFFu)* scf - nzs);
            b[3] = (bf16_t)((float)(q >> 24)          * scf - nzs);
            *(bf16x4*)&Bls[bcol * LDSS + prel * 4] = b;
        }
        __syncthreads();
        #pragma unroll
        for (int ks = 0; ks < 2; ++ks) {
            bf16x8 af[4], bfv[4];
            #pragma unroll
            for (int t = 0; t < 4; ++t) {
                af[t]  = *(const bf16x8*)&Als[(wm + t * 16 + lr) * LDSS + ks * 32 + lq * 8];
                bfv[t] = *(const bf16x8*)&Bls[(wn + t * 16 + lr) * LDSS + ks * 32 + lq * 8];
            }
            #pragma unroll
            for (int i = 0; i < 4; ++i)
                #pragma unroll
                for (int j = 0; j < 4; ++j)
                    acc[i][j] = __builtin_amdgcn_mfma_f32_16x16x32_bf16(af[i], bfv[j], acc[i][j], 0, 0, 0);
        }
        __syncthreads();
    }
    #pragma unroll
    for (int j = 0; j < 4; ++j) {
        const int col = n0 + wn + j * 16 + lr;
        const float bv = bias[col];
        #pragma unroll
        for (int i = 0; i < 4; ++i) {
            const int rbs = m0 + wm + i * 16 + lq * 4;
            #pragma unroll
            for (int r = 0; r < 4; ++r)
                out[(size_t)(rbs + r) * OUTFEAT + col] = acc[i][j][r] + bv;
        }
    }
}

extern "C" void kernel_launch(void* const* d_in, const int* in_sizes, int n_in,
                              void* d_out, int out_size, void* d_ws, size_t ws_size,
                              hipStream_t stream) {
    const float*        x      = (const float*)d_in[0];
    const unsigned int* qw     = (const unsigned int*)d_in[1];
    const float*        scales = (const float*)d_in[2];
    const int*          zeros  = (const int*)d_in[3];
    const float*        bias   = (const float*)d_in[4];
    float*              out    = (float*)d_out;

    const size_t xq_bytes = (size_t)TOKENS * INFEAT;         // 8 MB packed i8
    const size_t need = xq_bytes + TOKENS * (sizeof(float) + sizeof(int)) + 256;

    if (ws_size >= need) {
        unsigned int* xq = (unsigned int*)d_ws;
        float* xscale = (float*)((char*)d_ws + xq_bytes);
        int*   xsum   = (int*)((char*)d_ws + xq_bytes + TOKENS * sizeof(float));

        quant_x<<<dim3(TOKENS), dim3(256), 0, stream>>>(x, xq, xscale, xsum);
        q3gemm_i8<<<dim3((OUTFEAT / 128) * (TOKENS / 128)), dim3(256), 0, stream>>>(
            xq, qw, scales, zeros, bias, xscale, xsum, out);
    } else {
        q3gemm_fb<<<dim3(OUTFEAT / 128, TOKENS / 128), dim3(256), 0, stream>>>(
            x, qw, scales, zeros, bias, out);
    }
}

// Round 4
// 388.487 us; speedup vs baseline: 1.1197x; 1.1197x over previous
//
#include <hip/hip_runtime.h>
#include <hip/hip_bf16.h>

#define INFEAT 4096
#define OUTFEAT 11008
#define TOKENS 2048

typedef int v4i __attribute__((ext_vector_type(4)));
typedef __bf16 bf16_t;
typedef bf16_t bf16x4 __attribute__((ext_vector_type(4)));
typedef bf16_t bf16x8 __attribute__((ext_vector_type(8)));
typedef float f32x4 __attribute__((ext_vector_type(4)));

__device__ __forceinline__ void async_copy16(const void* g, void* l) {
    __builtin_amdgcn_global_load_lds((const __attribute__((address_space(1))) void*)g,
                                     (__attribute__((address_space(3))) void*)l,
                                     16, 0, 0);
}

// ---- pre-pass 1: per-token i8 quantization of x -> xq bytes [m][k],
// ---- xscale[m] = amax/127, xsum[m] = sum of quantized ints
__global__ __launch_bounds__(256) void quant_x(
    const float* __restrict__ x, unsigned int* __restrict__ xq,
    float* __restrict__ xscale, int* __restrict__ xsum)
{
    __shared__ float smax[4];
    __shared__ int ssum[4];
    const int row = blockIdx.x;
    const int tid = threadIdx.x;
    const int lane = tid & 63, wid = tid >> 6;
    const float* xr = x + (size_t)row * INFEAT;

    float4 v[4];
    #pragma unroll
    for (int i = 0; i < 4; ++i) v[i] = *(const float4*)&xr[tid * 16 + i * 4];

    float am = 0.f;
    #pragma unroll
    for (int i = 0; i < 4; ++i)
        am = fmaxf(am, fmaxf(fmaxf(fabsf(v[i].x), fabsf(v[i].y)),
                             fmaxf(fabsf(v[i].z), fabsf(v[i].w))));
    #pragma unroll
    for (int o = 32; o > 0; o >>= 1) am = fmaxf(am, __shfl_xor(am, o, 64));
    if (lane == 0) smax[wid] = am;
    __syncthreads();
    am = fmaxf(fmaxf(smax[0], smax[1]), fmaxf(smax[2], smax[3]));
    const float inv = am > 0.f ? 127.0f / am : 0.f;
    const float sc  = am > 0.f ? am / 127.0f : 0.f;

    int lsum = 0;
    unsigned int pk[4];
    #pragma unroll
    for (int i = 0; i < 4; ++i) {
        int q0 = (int)rintf(fminf(fmaxf(v[i].x * inv, -127.f), 127.f));
        int q1 = (int)rintf(fminf(fmaxf(v[i].y * inv, -127.f), 127.f));
        int q2 = (int)rintf(fminf(fmaxf(v[i].z * inv, -127.f), 127.f));
        int q3 = (int)rintf(fminf(fmaxf(v[i].w * inv, -127.f), 127.f));
        lsum += q0 + q1 + q2 + q3;
        pk[i] = (q0 & 255) | ((q1 & 255) << 8) | ((q2 & 255) << 16) | ((unsigned)(q3 & 255) << 24);
    }
    *(uint4*)&xq[(size_t)row * (INFEAT / 4) + tid * 4] = *(uint4*)pk;

    #pragma unroll
    for (int o = 32; o > 0; o >>= 1) lsum += __shfl_xor(lsum, o, 64);
    if (lane == 0) ssum[wid] = lsum;
    __syncthreads();
    if (tid == 0) {
        xsum[row] = ssum[0] + ssum[1] + ssum[2] + ssum[3];
        xscale[row] = sc;
    }
}

// ---- pre-pass 2: transpose packed weights -> wt[n][k] i8 bytes (w XOR 0x80 = w-128 signed)
// Tile: 64 n x 64 packed-rows (256 k). LDS word layout: row tn = 64 words (256B),
// chunk c (16B) stored at slot c ^ (tn & 15)  -> conflict-light both phases.
__global__ __launch_bounds__(256) void t_w(
    const unsigned int* __restrict__ qw, unsigned char* __restrict__ wt)
{
    __shared__ unsigned int Tw[64 * 64];   // 16 KB
    const int n0 = blockIdx.x * 64;
    const int kp0 = blockIdx.y * 64;
    const int tn = threadIdx.x & 63;
    const int tk4 = threadIdx.x >> 6;

    #pragma unroll
    for (int it = 0; it < 16; ++it) {
        const int kp = tk4 * 16 + it;
        const unsigned int q = qw[(size_t)(kp0 + kp) * OUTFEAT + n0 + tn] ^ 0x80808080u;
        const int slot = (kp >> 2) ^ (tn & 15);
        Tw[tn * 64 + slot * 4 + (kp & 3)] = q;
    }
    __syncthreads();

    #pragma unroll
    for (int i = 0; i < 4; ++i) {
        const int flat = i * 256 + threadIdx.x;
        const int n = flat >> 4;        // 0..63
        const int c = flat & 15;        // 16B chunk within 256B row
        uint4 v = *(const uint4*)&Tw[n * 64 + ((c ^ (n & 15)) * 4)];
        *(uint4*)&wt[(size_t)(n0 + n) * INFEAT + (size_t)kp0 * 4 + c * 16] = v;
    }
}

// ---- main GEMM: i8 MFMA, m97 structure, both operands [row][k] i8 bytes,
// ---- global_load_lds DMA + XOR chunk swizzle, all fragment reads ds_read_b128.
__global__ __launch_bounds__(256) void q3gemm_i8(
    const unsigned char* __restrict__ xqb, const unsigned char* __restrict__ wt,
    const float* __restrict__ scales, const int* __restrict__ zeros,
    const float* __restrict__ bias, const float* __restrict__ xscale,
    const int* __restrict__ xsum, float* __restrict__ out)
{
    __shared__ unsigned char Als[128 * 128];   // 16 KB: [m][k] bytes, chunk c at slot c^(m&7)
    __shared__ unsigned char Bls[128 * 128];   // 16 KB: [n][k] bytes

    const int tid = threadIdx.x;
    // n-panel grouping: 16 consecutive blocks share one weight panel (L2/L3 reuse)
    const int n0 = (blockIdx.x >> 4) * 128;
    const int m0 = (blockIdx.x & 15) * 128;

    const int wid = tid >> 6, lane = tid & 63;
    const int wm = (wid & 1) * 64, wn = (wid >> 1) * 64;
    const int lr = lane & 15, lq = lane >> 4;

    // DMA decomposition: wave stages rows wid*32 .. wid*32+31 (4 groups of 8 rows)
    const int rb0  = wid * 32;
    const int rsub = lane >> 3;      // 0..7
    const int sl   = lane & 7;       // destination chunk slot

    v4i acc[4][4];
    #pragma unroll
    for (int i = 0; i < 4; ++i)
        #pragma unroll
        for (int j = 0; j < 4; ++j)
            acc[i][j] = (v4i){0, 0, 0, 0};

    for (int kt = 0; kt < INFEAT / 128; ++kt) {
        const int k0 = kt * 128;

        #pragma unroll
        for (int p = 0; p < 4; ++p) {
            const int r = rb0 + p * 8 + rsub;
            const int s = sl ^ (r & 7);
            async_copy16(&xqb[(size_t)(m0 + r) * INFEAT + k0 + s * 16], Als + (rb0 + p * 8) * 128);
        }
        #pragma unroll
        for (int p = 0; p < 4; ++p) {
            const int r = rb0 + p * 8 + rsub;
            const int s = sl ^ (r & 7);
            async_copy16(&wt[(size_t)(n0 + r) * INFEAT + k0 + s * 16], Bls + (rb0 + p * 8) * 128);
        }

        __syncthreads();

        #pragma unroll
        for (int ks = 0; ks < 2; ++ks) {
            v4i af[4], bfv[4];
            #pragma unroll
            for (int t = 0; t < 4; ++t) {
                const int ra = wm + t * 16 + lr;
                const int pa = (ks * 4 + lq) ^ (ra & 7);
                af[t] = *(const v4i*)&Als[ra * 128 + pa * 16];
                const int rb = wn + t * 16 + lr;
                const int pb = (ks * 4 + lq) ^ (rb & 7);
                bfv[t] = *(const v4i*)&Bls[rb * 128 + pb * 16];
            }
            #pragma unroll
            for (int i = 0; i < 4; ++i)
                #pragma unroll
                for (int j = 0; j < 4; ++j)
                    acc[i][j] = __builtin_amdgcn_mfma_i32_16x16x64_i8(af[i], bfv[j], acc[i][j], 0, 0, 0);
        }

        __syncthreads();
    }

    // epilogue: out = sx[m]*s[n]*(acc + (128-z[n])*xsum[m]) + bias[n]
    #pragma unroll
    for (int j = 0; j < 4; ++j) {
        const int col = n0 + wn + j * 16 + lr;
        const float sn = scales[col];
        const int zi = 128 - zeros[col];
        const float bv = bias[col];
        #pragma unroll
        for (int i = 0; i < 4; ++i) {
            const int rb = m0 + wm + i * 16 + lq * 4;
            const float4 sx4 = *(const float4*)&xscale[rb];
            const int4 xs4 = *(const int4*)&xsum[rb];
            const float sxa[4] = {sx4.x, sx4.y, sx4.z, sx4.w};
            const int xsa[4] = {xs4.x, xs4.y, xs4.z, xs4.w};
            #pragma unroll
            for (int r = 0; r < 4; ++r) {
                const int tot = acc[i][j][r] + zi * xsa[r];
                out[(size_t)(rb + r) * OUTFEAT + col] = sxa[r] * sn * (float)tot + bv;
            }
        }
    }
}

// ---------------- fallback (round-1 fused kernel, used if ws too small) ----
#define LDSS 72
__global__ __launch_bounds__(256) void q3gemm_fb(
    const float* __restrict__ x, const unsigned int* __restrict__ qw,
    const float* __restrict__ scales, const int* __restrict__ zeros,
    const float* __restrict__ bias, float* __restrict__ out)
{
    __shared__ bf16_t Als[128 * LDSS];
    __shared__ bf16_t Bls[128 * LDSS];
    const int tid = threadIdx.x;
    const int m0 = blockIdx.y * 128;
    const int n0 = blockIdx.x * 128;
    const int bcol = tid & 127;
    const int bpr  = tid >> 7;
    const float scf = scales[n0 + bcol];
    const float nzs = (float)zeros[n0 + bcol] * scf;
    const int acolg = tid & 15;
    const int arow0 = tid >> 4;
    const int wid  = tid >> 6;
    const int lane = tid & 63;
    const int wm = (wid & 1) * 64;
    const int wn = (wid >> 1) * 64;
    const int lr = lane & 15;
    const int lq = lane >> 4;
    f32x4 acc[4][4];
    #pragma unroll
    for (int i = 0; i < 4; ++i)
        #pragma unroll
        for (int j = 0; j < 4; ++j) acc[i][j] = (f32x4)0.0f;
    for (int kt = 0; kt < INFEAT / 64; ++kt) {
        const int k0 = kt * 64;
        #pragma unroll
        for (int p = 0; p < 8; ++p) {
            const int row = arow0 + p * 16;
            const float4 v = *(const float4*)&x[(size_t)(m0 + row) * INFEAT + k0 + acolg * 4];
            bf16x4 b;
            b[0] = (bf16_t)v.x; b[1] = (bf16_t)v.y; b[2] = (bf16_t)v.z; b[3] = (bf16_t)v.w;
            *(bf16x4*)&Als[row * LDSS + acolg * 4] = b;
        }
        const int kp0 = k0 >> 2;
        #pragma unroll
        for (int it = 0; it < 8; ++it) {
            const int prel = it * 2 + bpr;
            const unsigned int q = qw[(size_t)(kp0 + prel) * OUTFEAT + n0 + bcol];
            bf16x4 b;
            b[0] = (bf16_t)((float)(q & 0xFFu)        * scf - nzs);
            b[1] = (bf16_t)((float)((q >> 8) & 0xFFu) * scf - nzs);
            b[2] = (bf16_t)((float)((q >> 16) & 0xFFu)* scf - nzs);
            b[3] = (bf16_t)((float)(q >> 24)          * scf - nzs);
            *(bf16x4*)&Bls[bcol * LDSS + prel * 4] = b;
        }
        __syncthreads();
        #pragma unroll
        for (int ks = 0; ks < 2; ++ks) {
            bf16x8 af[4], bfv[4];
            #pragma unroll
            for (int t = 0; t < 4; ++t) {
                af[t]  = *(const bf16x8*)&Als[(wm + t * 16 + lr) * LDSS + ks * 32 + lq * 8];
                bfv[t] = *(const bf16x8*)&Bls[(wn + t * 16 + lr) * LDSS + ks * 32 + lq * 8];
            }
            #pragma unroll
            for (int i = 0; i < 4; ++i)
                #pragma unroll
                for (int j = 0; j < 4; ++j)
                    acc[i][j] = __builtin_amdgcn_mfma_f32_16x16x32_bf16(af[i], bfv[j], acc[i][j], 0, 0, 0);
        }
        __syncthreads();
    }
    #pragma unroll
    for (int j = 0; j < 4; ++j) {
        const int col = n0 + wn + j * 16 + lr;
        const float bv = bias[col];
        #pragma unroll
        for (int i = 0; i < 4; ++i) {
            const int rbs = m0 + wm + i * 16 + lq * 4;
            #pragma unroll
            for (int r = 0; r < 4; ++r)
                out[(size_t)(rbs + r) * OUTFEAT + col] = acc[i][j][r] + bv;
        }
    }
}

extern "C" void kernel_launch(void* const* d_in, const int* in_sizes, int n_in,
                              void* d_out, int out_size, void* d_ws, size_t ws_size,
                              hipStream_t stream) {
    const float*        x      = (const float*)d_in[0];
    const unsigned int* qw     = (const unsigned int*)d_in[1];
    const float*        scales = (const float*)d_in[2];
    const int*          zeros  = (const int*)d_in[3];
    const float*        bias   = (const float*)d_in[4];
    float*              out    = (float*)d_out;

    const size_t wt_bytes = (size_t)OUTFEAT * INFEAT;        // 45.1 MB i8 transposed weights
    const size_t xq_bytes = (size_t)TOKENS * INFEAT;         // 8.4 MB packed i8 x
    const size_t need = wt_bytes + xq_bytes + TOKENS * (sizeof(float) + sizeof(int)) + 256;

    if (ws_size >= need) {
        unsigned char* wt = (unsigned char*)d_ws;
        unsigned int* xq  = (unsigned int*)((char*)d_ws + wt_bytes);
        float* xscale = (float*)((char*)d_ws + wt_bytes + xq_bytes);
        int*   xsum   = (int*)((char*)d_ws + wt_bytes + xq_bytes + TOKENS * sizeof(float));

        quant_x<<<dim3(TOKENS), dim3(256), 0, stream>>>(x, xq, xscale, xsum);
        t_w<<<dim3(OUTFEAT / 64, (INFEAT / 4) / 64), dim3(256), 0, stream>>>(qw, wt);
        q3gemm_i8<<<dim3((OUTFEAT / 128) * (TOKENS / 128)), dim3(256), 0, stream>>>(
            (const unsigned char*)xq, wt, scales, zeros, bias, xscale, xsum, out);
    } else {
        q3gemm_fb<<<dim3(OUTFEAT / 128, TOKENS / 128), dim3(256), 0, stream>>>(
            x, qw, scales, zeros, bias, out);
    }
}

// Round 5
// 295.388 us; speedup vs baseline: 1.4725x; 1.3152x over previous
//
#include <hip/hip_runtime.h>
#include <hip/hip_bf16.h>

#define INFEAT 4096
#define OUTFEAT 11008
#define TOKENS 2048

typedef int v4i __attribute__((ext_vector_type(4)));
typedef __bf16 bf16_t;
typedef bf16_t bf16x4 __attribute__((ext_vector_type(4)));
typedef bf16_t bf16x8 __attribute__((ext_vector_type(8)));
typedef float f32x4 __attribute__((ext_vector_type(4)));

__device__ __forceinline__ void async_copy16(const void* g, void* l) {
    __builtin_amdgcn_global_load_lds((const __attribute__((address_space(1))) void*)g,
                                     (__attribute__((address_space(3))) void*)l,
                                     16, 0, 0);
}

// ---- pre-pass 1: per-token i8 quantization of x -> xq bytes [m][k],
// ---- xscale[m] = amax/127, xsum[m] = sum of quantized ints
__global__ __launch_bounds__(256) void quant_x(
    const float* __restrict__ x, unsigned int* __restrict__ xq,
    float* __restrict__ xscale, int* __restrict__ xsum)
{
    __shared__ float smax[4];
    __shared__ int ssum[4];
    const int row = blockIdx.x;
    const int tid = threadIdx.x;
    const int lane = tid & 63, wid = tid >> 6;
    const float* xr = x + (size_t)row * INFEAT;

    float4 v[4];
    #pragma unroll
    for (int i = 0; i < 4; ++i) v[i] = *(const float4*)&xr[tid * 16 + i * 4];

    float am = 0.f;
    #pragma unroll
    for (int i = 0; i < 4; ++i)
        am = fmaxf(am, fmaxf(fmaxf(fabsf(v[i].x), fabsf(v[i].y)),
                             fmaxf(fabsf(v[i].z), fabsf(v[i].w))));
    #pragma unroll
    for (int o = 32; o > 0; o >>= 1) am = fmaxf(am, __shfl_xor(am, o, 64));
    if (lane == 0) smax[wid] = am;
    __syncthreads();
    am = fmaxf(fmaxf(smax[0], smax[1]), fmaxf(smax[2], smax[3]));
    const float inv = am > 0.f ? 127.0f / am : 0.f;
    const float sc  = am > 0.f ? am / 127.0f : 0.f;

    int lsum = 0;
    unsigned int pk[4];
    #pragma unroll
    for (int i = 0; i < 4; ++i) {
        int q0 = (int)rintf(fminf(fmaxf(v[i].x * inv, -127.f), 127.f));
        int q1 = (int)rintf(fminf(fmaxf(v[i].y * inv, -127.f), 127.f));
        int q2 = (int)rintf(fminf(fmaxf(v[i].z * inv, -127.f), 127.f));
        int q3 = (int)rintf(fminf(fmaxf(v[i].w * inv, -127.f), 127.f));
        lsum += q0 + q1 + q2 + q3;
        pk[i] = (q0 & 255) | ((q1 & 255) << 8) | ((q2 & 255) << 16) | ((unsigned)(q3 & 255) << 24);
    }
    *(uint4*)&xq[(size_t)row * (INFEAT / 4) + tid * 4] = *(uint4*)pk;

    #pragma unroll
    for (int o = 32; o > 0; o >>= 1) lsum += __shfl_xor(lsum, o, 64);
    if (lane == 0) ssum[wid] = lsum;
    __syncthreads();
    if (tid == 0) {
        xsum[row] = ssum[0] + ssum[1] + ssum[2] + ssum[3];
        xscale[row] = sc;
    }
}

// ---- pre-pass 2: transpose packed weights -> wt[n][k] i8 bytes (w XOR 0x80 = w-128 signed)
__global__ __launch_bounds__(256) void t_w(
    const unsigned int* __restrict__ qw, unsigned char* __restrict__ wt)
{
    __shared__ unsigned int Tw[64 * 64];   // 16 KB
    const int n0 = blockIdx.x * 64;
    const int kp0 = blockIdx.y * 64;
    const int tn = threadIdx.x & 63;
    const int tk4 = threadIdx.x >> 6;

    #pragma unroll
    for (int it = 0; it < 16; ++it) {
        const int kp = tk4 * 16 + it;
        const unsigned int q = qw[(size_t)(kp0 + kp) * OUTFEAT + n0 + tn] ^ 0x80808080u;
        const int slot = (kp >> 2) ^ (tn & 15);
        Tw[tn * 64 + slot * 4 + (kp & 3)] = q;
    }
    __syncthreads();

    #pragma unroll
    for (int i = 0; i < 4; ++i) {
        const int flat = i * 256 + threadIdx.x;
        const int n = flat >> 4;        // 0..63
        const int c = flat & 15;        // 16B chunk within 256B row
        uint4 v = *(const uint4*)&Tw[n * 64 + ((c ^ (n & 15)) * 4)];
        *(uint4*)&wt[(size_t)(n0 + n) * INFEAT + (size_t)kp0 * 4 + c * 16] = v;
    }
}

// ---- main GEMM: i8 MFMA, m97 structure, both operands [row][k] i8 bytes,
// ---- global_load_lds DMA + XOR chunk swizzle, all fragment reads ds_read_b128.
// __launch_bounds__(256,4): cap regs at 128/thread -> 4 blocks/CU resident
// (R4 at VGPR=140 sat at 3 blocks/CU, Occupancy 10.3% -> latency-bound).
__global__ __launch_bounds__(256, 4) void q3gemm_i8(
    const unsigned char* __restrict__ xqb, const unsigned char* __restrict__ wt,
    const float* __restrict__ scales, const int* __restrict__ zeros,
    const float* __restrict__ bias, const float* __restrict__ xscale,
    const int* __restrict__ xsum, float* __restrict__ out)
{
    __shared__ unsigned char Als[128 * 128];   // 16 KB: [m][k] bytes, chunk c at slot c^(m&7)
    __shared__ unsigned char Bls[128 * 128];   // 16 KB: [n][k] bytes

    const int tid = threadIdx.x;
    // n-panel grouping: 16 consecutive blocks share one weight panel (L2/L3 reuse)
    const int n0 = (blockIdx.x >> 4) * 128;
    const int m0 = (blockIdx.x & 15) * 128;

    const int wid = tid >> 6, lane = tid & 63;
    const int wm = (wid & 1) * 64, wn = (wid >> 1) * 64;
    const int lr = lane & 15, lq = lane >> 4;

    // DMA decomposition: wave stages rows wid*32 .. wid*32+31 (4 groups of 8 rows)
    const int rb0  = wid * 32;
    const int rsub = lane >> 3;      // 0..7
    const int sl   = lane & 7;       // destination chunk slot

    v4i acc[4][4];
    #pragma unroll
    for (int i = 0; i < 4; ++i)
        #pragma unroll
        for (int j = 0; j < 4; ++j)
            acc[i][j] = (v4i){0, 0, 0, 0};

    for (int kt = 0; kt < INFEAT / 128; ++kt) {
        const int k0 = kt * 128;

        #pragma unroll
        for (int p = 0; p < 4; ++p) {
            const int r = rb0 + p * 8 + rsub;
            const int s = sl ^ (r & 7);
            async_copy16(&xqb[(size_t)(m0 + r) * INFEAT + k0 + s * 16], Als + (rb0 + p * 8) * 128);
        }
        #pragma unroll
        for (int p = 0; p < 4; ++p) {
            const int r = rb0 + p * 8 + rsub;
            const int s = sl ^ (r & 7);
            async_copy16(&wt[(size_t)(n0 + r) * INFEAT + k0 + s * 16], Bls + (rb0 + p * 8) * 128);
        }

        __syncthreads();

        #pragma unroll
        for (int ks = 0; ks < 2; ++ks) {
            v4i af[4], bfv[4];
            #pragma unroll
            for (int t = 0; t < 4; ++t) {
                const int ra = wm + t * 16 + lr;
                const int pa = (ks * 4 + lq) ^ (ra & 7);
                af[t] = *(const v4i*)&Als[ra * 128 + pa * 16];
                const int rb = wn + t * 16 + lr;
                const int pb = (ks * 4 + lq) ^ (rb & 7);
                bfv[t] = *(const v4i*)&Bls[rb * 128 + pb * 16];
            }
            #pragma unroll
            for (int i = 0; i < 4; ++i)
                #pragma unroll
                for (int j = 0; j < 4; ++j)
                    acc[i][j] = __builtin_amdgcn_mfma_i32_16x16x64_i8(af[i], bfv[j], acc[i][j], 0, 0, 0);
        }

        __syncthreads();
    }

    // epilogue: out = sx[m]*s[n]*(acc + (128-z[n])*xsum[m]) + bias[n]
    #pragma unroll
    for (int j = 0; j < 4; ++j) {
        const int col = n0 + wn + j * 16 + lr;
        const float sn = scales[col];
        const int zi = 128 - zeros[col];
        const float bv = bias[col];
        #pragma unroll
        for (int i = 0; i < 4; ++i) {
            const int rb = m0 + wm + i * 16 + lq * 4;
            #pragma unroll
            for (int r = 0; r < 4; ++r) {
                const int tot = acc[i][j][r] + zi * xsum[rb + r];
                out[(size_t)(rb + r) * OUTFEAT + col] = xscale[rb + r] * sn * (float)tot + bv;
            }
        }
    }
}

// ---------------- fallback (round-1 fused kernel, used if ws too small) ----
#define LDSS 72
__global__ __launch_bounds__(256) void q3gemm_fb(
    const float* __restrict__ x, const unsigned int* __restrict__ qw,
    const float* __restrict__ scales, const int* __restrict__ zeros,
    const float* __restrict__ bias, float* __restrict__ out)
{
    __shared__ bf16_t Als[128 * LDSS];
    __shared__ bf16_t Bls[128 * LDSS];
    const int tid = threadIdx.x;
    const int m0 = blockIdx.y * 128;
    const int n0 = blockIdx.x * 128;
    const int bcol = tid & 127;
    const int bpr  = tid >> 7;
    const float scf = scales[n0 + bcol];
    const float nzs = (float)zeros[n0 + bcol] * scf;
    const int acolg = tid & 15;
    const int arow0 = tid >> 4;
    const int wid  = tid >> 6;
    const int lane = tid & 63;
    const int wm = (wid & 1) * 64;
    const int wn = (wid >> 1) * 64;
    const int lr = lane & 15;
    const int lq = lane >> 4;
    f32x4 acc[4][4];
    #pragma unroll
    for (int i = 0; i < 4; ++i)
        #pragma unroll
        for (int j = 0; j < 4; ++j) acc[i][j] = (f32x4)0.0f;
    for (int kt = 0; kt < INFEAT / 64; ++kt) {
        const int k0 = kt * 64;
        #pragma unroll
        for (int p = 0; p < 8; ++p) {
            const int row = arow0 + p * 16;
            const float4 v = *(const float4*)&x[(size_t)(m0 + row) * INFEAT + k0 + acolg * 4];
            bf16x4 b;
            b[0] = (bf16_t)v.x; b[1] = (bf16_t)v.y; b[2] = (bf16_t)v.z; b[3] = (bf16_t)v.w;
            *(bf16x4*)&Als[row * LDSS + acolg * 4] = b;
        }
        const int kp0 = k0 >> 2;
        #pragma unroll
        for (int it = 0; it < 8; ++it) {
            const int prel = it * 2 + bpr;
            const unsigned int q = qw[(size_t)(kp0 + prel) * OUTFEAT + n0 + bcol];
            bf16x4 b;
            b[0] = (bf16_t)((float)(q & 0xFFu)        * scf - nzs);
            b[1] = (bf16_t)((float)((q >> 8) & 0xFFu) * scf - nzs);
            b[2] = (bf16_t)((float)((q >> 16) & 0xFFu)* scf - nzs);
            b[3] = (bf16_t)((float)(q >> 24)          * scf - nzs);
            *(bf16x4*)&Bls[bcol * LDSS + prel * 4] = b;
        }
        __syncthreads();
        #pragma unroll
        for (int ks = 0; ks < 2; ++ks) {
            bf16x8 af[4], bfv[4];
            #pragma unroll
            for (int t = 0; t < 4; ++t) {
                af[t]  = *(const bf16x8*)&Als[(wm + t * 16 + lr) * LDSS + ks * 32 + lq * 8];
                bfv[t] = *(const bf16x8*)&Bls[(wn + t * 16 + lr) * LDSS + ks * 32 + lq * 8];
            }
            #pragma unroll
            for (int i = 0; i < 4; ++i)
                #pragma unroll
                for (int j = 0; j < 4; ++j)
                    acc[i][j] = __builtin_amdgcn_mfma_f32_16x16x32_bf16(af[i], bfv[j], acc[i][j], 0, 0, 0);
        }
        __syncthreads();
    }
    #pragma unroll
    for (int j = 0; j < 4; ++j) {
        const int col = n0 + wn + j * 16 + lr;
        const float bv = bias[col];
        #pragma unroll
        for (int i = 0; i < 4; ++i) {
            const int rbs = m0 + wm + i * 16 + lq * 4;
            #pragma unroll
            for (int r = 0; r < 4; ++r)
                out[(size_t)(rbs + r) * OUTFEAT + col] = acc[i][j][r] + bv;
        }
    }
}

extern "C" void kernel_launch(void* const* d_in, const int* in_sizes, int n_in,
                              void* d_out, int out_size, void* d_ws, size_t ws_size,
                              hipStream_t stream) {
    const float*        x      = (const float*)d_in[0];
    const unsigned int* qw     = (const unsigned int*)d_in[1];
    const float*        scales = (const float*)d_in[2];
    const int*          zeros  = (const int*)d_in[3];
    const float*        bias   = (const float*)d_in[4];
    float*              out    = (float*)d_out;

    const size_t wt_bytes = (size_t)OUTFEAT * INFEAT;        // 45.1 MB i8 transposed weights
    const size_t xq_bytes = (size_t)TOKENS * INFEAT;         // 8.4 MB packed i8 x
    const size_t need = wt_bytes + xq_bytes + TOKENS * (sizeof(float) + sizeof(int)) + 256;

    if (ws_size >= need) {
        unsigned char* wt = (unsigned char*)d_ws;
        unsigned int* xq  = (unsigned int*)((char*)d_ws + wt_bytes);
        float* xscale = (float*)((char*)d_ws + wt_bytes + xq_bytes);
        int*   xsum   = (int*)((char*)d_ws + wt_bytes + xq_bytes + TOKENS * sizeof(float));

        quant_x<<<dim3(TOKENS), dim3(256), 0, stream>>>(x, xq, xscale, xsum);
        t_w<<<dim3(OUTFEAT / 64, (INFEAT / 4) / 64), dim3(256), 0, stream>>>(qw, wt);
        q3gemm_i8<<<dim3((OUTFEAT / 128) * (TOKENS / 128)), dim3(256), 0, stream>>>(
            (const unsigned char*)xq, wt, scales, zeros, bias, xscale, xsum, out);
    } else {
        q3gemm_fb<<<dim3(OUTFEAT / 128, TOKENS / 128), dim3(256), 0, stream>>>(
            x, qw, scales, zeros, bias, out);
    }
}